// Round 1
// baseline (21033.220 us; speedup 1.0000x reference)
//
#include <hip/hip_runtime.h>
#include <stdint.h>

typedef __attribute__((ext_vector_type(8))) short s16x8;
typedef __attribute__((ext_vector_type(4))) float f32x4;
typedef uint32_t u32;

#define DEV static __device__ __forceinline__

constexpr int T_ = 1024;
constexpr int GW = 16;   // workgroups per batch-group

DEV u32 bf16rne(float x){
  u32 u = __float_as_uint(x);
  u = (u + 0x7FFFu + ((u >> 16) & 1u)) >> 16;
  return u;
}
DEV float sigm_(float x){ return 1.f / (1.f + __expf(-x)); }
DEV float tanh_(float x){
  float ax = fabsf(x);
  float e = __expf(-2.f * ax);
  float r = (1.f - e) / (1.f + e);
  return x < 0.f ? -r : r;
}
DEV f32x4 mfma_(s16x8 a, s16x8 b, f32x4 c){
  return __builtin_amdgcn_mfma_f32_16x16x32_bf16(a, b, c, 0, 0, 0);
}

// copy nblk fragment blocks (1KB each: [64 lanes][8 shorts]) global->LDS
DEV void stageN(const short* __restrict__ g, short* l, int nblk, int wv, int lane){
  for (int c = wv; c < nblk; c += 4){
    s16x8 v = *(const s16x8*)(g + c*512 + lane*8);
    *(s16x8*)(l + c*512 + lane*8) = v;
  }
}

// group barrier among GW workgroups (device-scope; sense via monotonically
// increasing generation counter)
DEV void groupbar(u32* ctr, u32* gen, u32 target){
  __syncthreads();                     // drains vmcnt: all waves' stores at L2
  if (threadIdx.x == 0){
    __threadfence();
    u32 prev = __hip_atomic_fetch_add(ctr, 1u, __ATOMIC_ACQ_REL, __HIP_MEMORY_SCOPE_AGENT);
    if (prev == GW - 1u){
      __hip_atomic_store(ctr, 0u, __ATOMIC_RELAXED, __HIP_MEMORY_SCOPE_AGENT);
      __hip_atomic_fetch_add(gen, 1u, __ATOMIC_RELEASE, __HIP_MEMORY_SCOPE_AGENT);
    } else {
      while (__hip_atomic_load(gen, __ATOMIC_ACQUIRE, __HIP_MEMORY_SCOPE_AGENT) < target){
        __builtin_amdgcn_s_sleep(1);
      }
    }
    __threadfence();                   // agent acquire: invalidates this CU's L1
  }
  __syncthreads();
}

// ---------------------------------------------------------------------------
// Fused 2-cell LSTM scan. One batch-group (16 rows) per 16 consecutive blocks.
// Fragment layouts everywhere: A-block[lane][e] = A[row=lane&15][k=(lane>>4)*8+e]
// cell1: gates[16,2048] = [x(K=32*KXB) | h1(512)] @ W1^T ; h-slice 32 cols/WG
// cell2: gates[16,1024] = [h1(512) | h2(256)] @ W2^T    ; h-slice 16 cols/WG
// seq holds the cell2 output sequence (z or d), slot t+1 = output of step t;
// slot t doubles as the h2 state input of step t. One barrier per step.
// ---------------------------------------------------------------------------
template<int KXB>
__launch_bounds__(256, 1)
__global__ void scan_kernel(const short* __restrict__ xsrc,  // [T][4][KXB][512]
                            short* __restrict__ seq,         // [T+1][4][8][512]
                            short* __restrict__ h1f,         // [2][4][16][512]
                            const short* __restrict__ w1p,   // [128][KXB+16][512]
                            const short* __restrict__ w2p,   // [64][24][512]
                            const float* __restrict__ bc1,   // [2048]
                            const float* __restrict__ bc2,   // [1024]
                            u32* __restrict__ bar)
{
  constexpr int KS1 = KXB + 16;
  constexpr int KS2 = 24;
  const int bg   = blockIdx.x >> 4;
  const int w    = blockIdx.x & 15;
  const int tid  = threadIdx.x;
  const int wv   = tid >> 6;
  const int lane = tid & 63;

  __shared__ short lx[8*512];
  __shared__ short lh1[16*512];
  __shared__ short lh2[8*512];
  __shared__ float g1[4][16*33];
  __shared__ float g2[4][16*17];
  __shared__ float c1s[16*32];
  __shared__ float c2s[16*16];
  __shared__ float b1s[4][32];
  __shared__ float b2s[4][16];

  for (int i = tid; i < 16*32; i += 256) c1s[i] = 0.f;
  for (int i = tid; i < 16*16; i += 256) c2s[i] = 0.f;
  if (tid < 128) b1s[tid>>5][tid&31] = bc1[(tid>>5)*512 + w*32 + (tid&31)];
  if (tid < 64)  b2s[tid>>4][tid&15] = bc2[(tid>>4)*256 + w*16 + (tid&15)];

  // weights -> registers (persistent)
  s16x8 W1[2][KS1];
  s16x8 W2[KS2];
  {
    const int nt0 = wv*32 + w*2;            // gate wv, 32-col strip of WG w
    #pragma unroll
    for (int nt = 0; nt < 2; ++nt)
      #pragma unroll
      for (int ks = 0; ks < KS1; ++ks)
        W1[nt][ks] = *(const s16x8*)(w1p + (((nt0+nt)*KS1 + ks)*64 + lane)*8);
    const int nt2 = wv*16 + w;
    #pragma unroll
    for (int ks = 0; ks < KS2; ++ks)
      W2[ks] = *(const s16x8*)(w2p + ((nt2*KS2 + ks)*64 + lane)*8);
  }

  // prologue: x(t=0); h1_{-1}=0 lives in buffer 1 (pre-zeroed)
  stageN(xsrc + (0*4 + bg)*KXB*512, lx, KXB, wv, lane);
  stageN(h1f + (1*4 + bg)*16*512,  lh1, 16,  wv, lane);
  __syncthreads();

  u32 mygen = 0;
  for (int t = 0; t < T_; ++t){
    // ---- cell1: gates slice, wave wv = gate wv, cols w*32..+32 ----
    f32x4 acc0 = {0.f,0.f,0.f,0.f}, acc1 = {0.f,0.f,0.f,0.f};
    #pragma unroll
    for (int ks = 0; ks < KS1; ++ks){
      const short* ap = (ks < KXB) ? (lx + ks*512) : (lh1 + (ks-KXB)*512);
      s16x8 a = *(const s16x8*)(ap + lane*8);
      acc0 = mfma_(a, W1[0][ks], acc0);
      acc1 = mfma_(a, W1[1][ks], acc1);
    }
    {
      const int r0 = (lane>>4)*4, cc = lane & 15;
      #pragma unroll
      for (int j = 0; j < 4; ++j){
        g1[wv][(r0+j)*33 + cc]      = acc0[j];
        g1[wv][(r0+j)*33 + 16 + cc] = acc1[j];
      }
    }
    __syncthreads();
    // elementwise: h1 slice [16 rows x 32 cols], 2 outputs/thread
    {
      short* h1dst = h1f + (((t&1)*4 + bg)*16 + w)*512;
      const int idx = tid << 1;
      const int r = idx >> 5;
      const int c = idx & 31;        // even
      float hv0 = 0.f, hv1 = 0.f;
      #pragma unroll
      for (int p = 0; p < 2; ++p){
        const int cp = c + p;
        const float xi = g1[0][r*33+cp] + b1s[0][cp];
        const float xf = g1[1][r*33+cp] + b1s[1][cp];
        const float xg = g1[2][r*33+cp] + b1s[2][cp];
        const float xo = g1[3][r*33+cp] + b1s[3][cp];
        const float ii = sigm_(xi), ff = sigm_(xf), oo = sigm_(xo);
        const float gg = tanh_(xg);
        const float cn = ff * c1s[r*32+cp] + ii * gg;
        c1s[r*32+cp] = cn;
        const float hv = oo * tanh_(cn);
        if (p == 0) hv0 = hv; else hv1 = hv;
      }
      const u32 pk = bf16rne(hv0) | (bf16rne(hv1) << 16);
      *(u32*)(h1dst + ((((c>>3)<<4) + r) << 3) + (c & 7)) = pk;
    }

    ++mygen;
    groupbar(bar + bg*64, bar + bg*64 + 32, mygen);

    // ---- stage: h1_t (all slices), h2_{t-1} (= seq slot t), x_{t+1} ----
    stageN(h1f + ((t&1)*4 + bg)*16*512, lh1, 16, wv, lane);
    stageN(seq + (t*4 + bg)*8*512,      lh2, 8,  wv, lane);
    const int tn = (t+1 < T_) ? (t+1) : (T_-1);
    stageN(xsrc + (tn*4 + bg)*KXB*512,  lx, KXB, wv, lane);
    __syncthreads();

    // ---- cell2: A = [h1_t | h2_{t-1}], wave wv = gate wv, cols w*16..+16 ----
    f32x4 acc = {0.f,0.f,0.f,0.f};
    #pragma unroll
    for (int ks = 0; ks < KS2; ++ks){
      const short* ap = (ks < 16) ? (lh1 + ks*512) : (lh2 + (ks-16)*512);
      s16x8 a = *(const s16x8*)(ap + lane*8);
      acc = mfma_(a, W2[ks], acc);
    }
    {
      const int r0 = (lane>>4)*4, cc = lane & 15;
      #pragma unroll
      for (int j = 0; j < 4; ++j) g2[wv][(r0+j)*17 + cc] = acc[j];
    }
    __syncthreads();
    {
      short* odst = seq + ((t+1)*4 + bg)*8*512;
      const int r = tid >> 4, c = tid & 15;
      const float xi = g2[0][r*17+c] + b2s[0][c];
      const float xf = g2[1][r*17+c] + b2s[1][c];
      const float xg = g2[2][r*17+c] + b2s[2][c];
      const float xo = g2[3][r*17+c] + b2s[3][c];
      const float ii = sigm_(xi), ff = sigm_(xf), oo = sigm_(xo);
      const float gg = tanh_(xg);
      const float cn = ff * c2s[r*16+c] + ii * gg;
      c2s[r*16+c] = cn;
      const float hv = oo * tanh_(cn);
      const int jj = ((w & 1) << 4) + c;           // k-local within 32-block
      odst[(((w>>1)*64 + ((jj>>3)<<4) + r) << 3) + (jj & 7)] = (short)bf16rne(hv);
    }
    // no trailing sync needed: next write to lh1/lh2/lx is after next barrier
  }
}

// ---------------------------------------------------------------------------
// fused fc1(relu)+fc2 over one t-slice (64 rows) per block
// ---------------------------------------------------------------------------
__launch_bounds__(256, 1)
__global__ void fc_kernel(const short* __restrict__ dfrag, // [T+1][4][8][512]
                          const short* __restrict__ fc1p,  // [32][8][512]
                          const short* __restrict__ fc2p,  // [8][16][512]
                          const float* __restrict__ fc1b,  // [512]
                          float* __restrict__ out)         // [64][1024][128]
{
  const int t = blockIdx.x;
  const int tid = threadIdx.x, wv = tid >> 6, lane = tid & 63;
  __shared__ short hl[4*16*512];                 // 64KB: h in frag layout
  const short* A = dfrag + (t+1)*4*8*512;

  f32x4 acc[4][8];
  #pragma unroll
  for (int mt = 0; mt < 4; ++mt)
    #pragma unroll
    for (int nt = 0; nt < 8; ++nt) acc[mt][nt] = (f32x4){0.f,0.f,0.f,0.f};

  #pragma unroll
  for (int ks = 0; ks < 8; ++ks){
    s16x8 a[4];
    #pragma unroll
    for (int mt = 0; mt < 4; ++mt) a[mt] = *(const s16x8*)(A + (mt*8+ks)*512 + lane*8);
    #pragma unroll
    for (int nt = 0; nt < 8; ++nt){
      s16x8 b = *(const s16x8*)(fc1p + (((wv*8+nt)*8 + ks)*64 + lane)*8);
      #pragma unroll
      for (int mt = 0; mt < 4; ++mt) acc[mt][nt] = mfma_(a[mt], b, acc[mt][nt]);
    }
  }
  const int r0 = (lane>>4)*4, c15 = lane & 15;
  #pragma unroll
  for (int nt = 0; nt < 8; ++nt){
    const int col = wv*128 + nt*16 + c15;
    const float bia = fc1b[col];
    const int ks2 = col >> 5, lp = (((col & 31) >> 3) << 4), e = col & 7;
    #pragma unroll
    for (int mt = 0; mt < 4; ++mt)
      #pragma unroll
      for (int j = 0; j < 4; ++j){
        float v = acc[mt][nt][j] + bia;
        v = v > 0.f ? v : 0.f;
        hl[(mt*16 + ks2)*512 + (lp + r0 + j)*8 + e] = (short)bf16rne(v);
      }
  }
  __syncthreads();

  f32x4 a2[4][2];
  #pragma unroll
  for (int mt = 0; mt < 4; ++mt)
    #pragma unroll
    for (int nt = 0; nt < 2; ++nt) a2[mt][nt] = (f32x4){0.f,0.f,0.f,0.f};
  #pragma unroll
  for (int ks = 0; ks < 16; ++ks){
    s16x8 a[4];
    #pragma unroll
    for (int mt = 0; mt < 4; ++mt) a[mt] = *(const s16x8*)(hl + (mt*16+ks)*512 + lane*8);
    #pragma unroll
    for (int nt = 0; nt < 2; ++nt){
      s16x8 b = *(const s16x8*)(fc2p + (((wv*2+nt)*16 + ks)*64 + lane)*8);
      #pragma unroll
      for (int mt = 0; mt < 4; ++mt) a2[mt][nt] = mfma_(a[mt], b, a2[mt][nt]);
    }
  }
  #pragma unroll
  for (int mt = 0; mt < 4; ++mt)
    #pragma unroll
    for (int nt = 0; nt < 2; ++nt)
      #pragma unroll
      for (int j = 0; j < 4; ++j){
        const int b_  = mt*16 + r0 + j;
        const int col = wv*32 + nt*16 + c15;
        out[(b_*1024 + t)*128 + col] = a2[mt][nt][j];
      }
}

// ---------------------------------------------------------------------------
// packing kernels
// ---------------------------------------------------------------------------
// W[N][K1] ++ W2[N][K2] -> bf16 fragment layout [N/16][KS][64][8]
__global__ void pack_w(const float* __restrict__ src1, int K1,
                       const float* __restrict__ src2, int K2,
                       int N, short* __restrict__ dst)
{
  const int KS = (K1 + K2) >> 5;
  const int total = (N >> 4) * KS * 64;
  const int tid = blockIdx.x*256 + threadIdx.x;
  if (tid >= total) return;
  const int lane = tid & 63;
  const int rest = tid >> 6;
  const int ks = rest % KS;
  const int ntile = rest / KS;
  const int n = ntile*16 + (lane & 15);
  const int k = ks*32 + ((lane >> 4) << 3);
  const float* s; int kk, stride;
  if (k < K1){ s = src1; kk = k;      stride = K1; }
  else       { s = src2; kk = k - K1; stride = K2; }
  const float4 f0 = *(const float4*)(s + n*stride + kk);
  const float4 f1 = *(const float4*)(s + n*stride + kk + 4);
  s16x8 r;
  r[0] = (short)bf16rne(f0.x); r[1] = (short)bf16rne(f0.y);
  r[2] = (short)bf16rne(f0.z); r[3] = (short)bf16rne(f0.w);
  r[4] = (short)bf16rne(f1.x); r[5] = (short)bf16rne(f1.y);
  r[6] = (short)bf16rne(f1.z); r[7] = (short)bf16rne(f1.w);
  *(s16x8*)(dst + tid*8) = r;
}

// x[64][1024][128] fp32 -> [T][4][4][512] bf16 frag layout
__global__ void pack_x_k(const float* __restrict__ x, short* __restrict__ xp){
  const int tid = blockIdx.x*256 + threadIdx.x;     // 1,048,576 threads
  const int lane = tid & 63;
  const int ks = (tid >> 6) & 3;
  const int bg = (tid >> 8) & 3;
  const int t  = tid >> 10;
  const int b  = bg*16 + (lane & 15);
  const int k  = ks*32 + ((lane >> 4) << 3);
  const float* s = x + (b*1024 + t)*128 + k;
  const float4 f0 = *(const float4*)s;
  const float4 f1 = *(const float4*)(s + 4);
  s16x8 r;
  r[0] = (short)bf16rne(f0.x); r[1] = (short)bf16rne(f0.y);
  r[2] = (short)bf16rne(f0.z); r[3] = (short)bf16rne(f0.w);
  r[4] = (short)bf16rne(f1.x); r[5] = (short)bf16rne(f1.y);
  r[6] = (short)bf16rne(f1.z); r[7] = (short)bf16rne(f1.w);
  *(s16x8*)(xp + (size_t)tid*8) = r;
}

__global__ void addv(const float* __restrict__ a, const float* __restrict__ b,
                     float* __restrict__ o, int n){
  const int i = blockIdx.x*256 + threadIdx.x;
  if (i < n) o[i] = a[i] + b[i];
}

// ---------------------------------------------------------------------------
extern "C" void kernel_launch(void* const* d_in, const int* in_sizes, int n_in,
                              void* d_out, int out_size, void* d_ws, size_t ws_size,
                              hipStream_t stream)
{
  (void)in_sizes; (void)n_in; (void)out_size; (void)ws_size;
  const float* x     = (const float*)d_in[0];
  const float* eWih1 = (const float*)d_in[1];
  const float* eWhh1 = (const float*)d_in[2];
  const float* ebih1 = (const float*)d_in[3];
  const float* ebhh1 = (const float*)d_in[4];
  const float* eWih2 = (const float*)d_in[5];
  const float* eWhh2 = (const float*)d_in[6];
  const float* ebih2 = (const float*)d_in[7];
  const float* ebhh2 = (const float*)d_in[8];
  const float* dWih1 = (const float*)d_in[9];
  const float* dWhh1 = (const float*)d_in[10];
  const float* dbih1 = (const float*)d_in[11];
  const float* dbhh1 = (const float*)d_in[12];
  const float* dWih2 = (const float*)d_in[13];
  const float* dWhh2 = (const float*)d_in[14];
  const float* dbih2 = (const float*)d_in[15];
  const float* dbhh2 = (const float*)d_in[16];
  const float* fc1w  = (const float*)d_in[17];
  const float* fc1b  = (const float*)d_in[18];
  const float* fc2w  = (const float*)d_in[19];
  float* out = (float*)d_out;
  char* ws = (char*)d_ws;

  size_t off = 0;
  auto alloc = [&](size_t bytes){ size_t o = off; off += (bytes + 255) & ~(size_t)255; return o; };
  const size_t ENC1P = alloc(128*20*512*2);
  const size_t ENC2P = alloc(64*24*512*2);
  const size_t DEC1P = alloc(128*24*512*2);
  const size_t DEC2P = alloc(64*24*512*2);
  const size_t FC1P  = alloc(32*8*512*2);
  const size_t FC2P  = alloc(8*16*512*2);
  const size_t BC1E  = alloc(2048*4);
  const size_t BC2E  = alloc(1024*4);
  const size_t BC1D  = alloc(2048*4);
  const size_t BC2D  = alloc(1024*4);
  const size_t XP    = alloc((size_t)1024*4*4*512*2);
  const size_t ZFRAG = alloc((size_t)1025*4*8*512*2);
  const size_t DFRAG = alloc((size_t)1025*4*8*512*2);
  const size_t H1E   = alloc(2*4*16*512*2);
  const size_t H1D   = alloc(2*4*16*512*2);
  const size_t BAR   = alloc(8192);

  short* enc1p = (short*)(ws + ENC1P);
  short* enc2p = (short*)(ws + ENC2P);
  short* dec1p = (short*)(ws + DEC1P);
  short* dec2p = (short*)(ws + DEC2P);
  short* fc1p  = (short*)(ws + FC1P);
  short* fc2p  = (short*)(ws + FC2P);
  float* bc1e  = (float*)(ws + BC1E);
  float* bc2e  = (float*)(ws + BC2E);
  float* bc1d  = (float*)(ws + BC1D);
  float* bc2d  = (float*)(ws + BC2D);
  short* xp    = (short*)(ws + XP);
  short* zfrag = (short*)(ws + ZFRAG);
  short* dfrag = (short*)(ws + DFRAG);
  short* h1e   = (short*)(ws + H1E);
  short* h1d   = (short*)(ws + H1D);
  u32*   bar   = (u32*)(ws + BAR);

  // per-launch state init (ws is poisoned once; we re-init every launch)
  hipMemsetAsync(zfrag, 0, 4*8*512*2, stream);          // z slot 0  (h2 state t=0)
  hipMemsetAsync(dfrag, 0, 4*8*512*2, stream);          // d slot 0
  hipMemsetAsync(h1e, 0, 2*4*16*512*2, stream);
  hipMemsetAsync(h1d, 0, 2*4*16*512*2, stream);
  hipMemsetAsync(bar, 0, 8192, stream);

  // weight/bias/x packing
  pack_w<<<640, 256, 0, stream>>>(eWih1, 128, eWhh1, 512, 2048, enc1p);
  pack_w<<<384, 256, 0, stream>>>(eWih2, 512, eWhh2, 256, 1024, enc2p);
  pack_w<<<768, 256, 0, stream>>>(dWih1, 256, dWhh1, 512, 2048, dec1p);
  pack_w<<<384, 256, 0, stream>>>(dWih2, 512, dWhh2, 256, 1024, dec2p);
  pack_w<<<64,  256, 0, stream>>>(fc1w,  256, fc1w,  0,   512,  fc1p);
  pack_w<<<32,  256, 0, stream>>>(fc2w,  512, fc2w,  0,   128,  fc2p);
  addv<<<8, 256, 0, stream>>>(ebih1, ebhh1, bc1e, 2048);
  addv<<<4, 256, 0, stream>>>(ebih2, ebhh2, bc2e, 1024);
  addv<<<8, 256, 0, stream>>>(dbih1, dbhh1, bc1d, 2048);
  addv<<<4, 256, 0, stream>>>(dbih2, dbhh2, bc2d, 1024);
  pack_x_k<<<4096, 256, 0, stream>>>(x, xp);

  // encoder scan: x -> z
  scan_kernel<4><<<64, 256, 0, stream>>>(xp, zfrag, h1e, enc1p, enc2p,
                                         bc1e, bc2e, bar);
  // decoder scan: z -> d   (x source = zfrag shifted by one slot: slot t = z_t)
  scan_kernel<8><<<64, 256, 0, stream>>>(zfrag + 4*8*512, dfrag, h1d, dec1p, dec2p,
                                         bc1d, bc2d, bar + 1024);
  // fc1(relu)+fc2
  fc_kernel<<<1024, 256, 0, stream>>>(dfrag, fc1p, fc2p, fc1b, out);
}

// Round 2
// 10273.777 us; speedup vs baseline: 2.0473x; 2.0473x over previous
//
#include <hip/hip_runtime.h>
#include <stdint.h>

typedef __attribute__((ext_vector_type(8))) short s16x8;
typedef __attribute__((ext_vector_type(4))) float f32x4;
typedef uint32_t u32;

#define DEV static __device__ __forceinline__

constexpr int T_ = 1024;
constexpr int GW = 16;   // workgroups per batch-group

DEV u32 bf16rne(float x){
  u32 u = __float_as_uint(x);
  u = (u + 0x7FFFu + ((u >> 16) & 1u)) >> 16;
  return u;
}
DEV float sigm_(float x){ return 1.f / (1.f + __expf(-x)); }
DEV float tanh_(float x){
  float ax = fabsf(x);
  float e = __expf(-2.f * ax);
  float r = (1.f - e) / (1.f + e);
  return x < 0.f ? -r : r;
}
DEV f32x4 mfma_(s16x8 a, s16x8 b, f32x4 c){
  return __builtin_amdgcn_mfma_f32_16x16x32_bf16(a, b, c, 0, 0, 0);
}

// --- system-coherent (LLC-level) access helpers: bypass L1+L2, NO fences ---
DEV s16x8 ldg_cc16(const short* p){
  s16x8 v;
  asm volatile("global_load_dwordx4 %0, %1, off sc0 sc1"
               : "=v"(v) : "v"(p) : "memory");
  return v;
}
DEV void stg_cc4(short* p, u32 v){
  asm volatile("global_store_dword %0, %1, off sc0 sc1"
               : : "v"(p), "v"(v) : "memory");
}
DEV void stg_cc2(short* p, u32 v){
  asm volatile("global_store_short %0, %1, off sc0 sc1"
               : : "v"(p), "v"(v) : "memory");
}
DEV void wait_vm0(){ asm volatile("s_waitcnt vmcnt(0)" ::: "memory"); }

// copy nblk fragment blocks (1KB each) global->LDS (prologue only, cached ok)
DEV void stageN(const short* __restrict__ g, short* l, int nblk, int wv, int lane){
  for (int c = wv; c < nblk; c += 4){
    s16x8 v = *(const s16x8*)(g + c*512 + lane*8);
    *(s16x8*)(l + c*512 + lane*8) = v;
  }
}

// group barrier among GW workgroups. NO cache maintenance: all cross-WG data
// moves via sc0sc1 (LLC-coherent) accesses, so relaxed atomics + vmcnt drains
// are sufficient. Parity-indexed arrival counters avoid the reset race.
// base layout (u32): [0]=ctr_even, [32]=ctr_odd, [64]=gen
DEV void groupbar(u32* base, u32 t, u32 target){
  wait_vm0();                          // our sc0sc1 stores are LLC-visible
  __syncthreads();
  if (threadIdx.x == 0){
    u32* ctr = base + (t & 1u)*32;
    u32* gen = base + 64;
    u32 prev = __hip_atomic_fetch_add(ctr, 1u, __ATOMIC_RELAXED, __HIP_MEMORY_SCOPE_AGENT);
    if (prev == GW - 1u){
      __hip_atomic_store(ctr, 0u, __ATOMIC_RELAXED, __HIP_MEMORY_SCOPE_AGENT);
      wait_vm0();                      // ctr reset visible before gen bump
      __hip_atomic_fetch_add(gen, 1u, __ATOMIC_RELAXED, __HIP_MEMORY_SCOPE_AGENT);
    } else {
      while (__hip_atomic_load(gen, __ATOMIC_RELAXED, __HIP_MEMORY_SCOPE_AGENT) < target){
        __builtin_amdgcn_s_sleep(1);
      }
    }
  }
  __syncthreads();
}

// ---------------------------------------------------------------------------
// Fused 2-cell LSTM scan. One batch-group (16 rows) per 16 consecutive blocks.
// Fragment layouts everywhere: A-block[lane][e] = A[row=lane&15][k=(lane>>4)*8+e]
// ---------------------------------------------------------------------------
template<int KXB>
__launch_bounds__(256, 1)
__global__ void scan_kernel(const short* __restrict__ xsrc,  // [T][4][KXB][512]
                            short* __restrict__ seq,         // [T+1][4][8][512]
                            short* __restrict__ h1f,         // [2][4][16][512]
                            const short* __restrict__ w1p,   // [128][KXB+16][512]
                            const short* __restrict__ w2p,   // [64][24][512]
                            const float* __restrict__ bc1,   // [2048]
                            const float* __restrict__ bc2,   // [1024]
                            u32* __restrict__ bar)
{
  constexpr int KS1 = KXB + 16;
  constexpr int KS2 = 24;
  constexpr int XB  = KXB/4;
  const int bg   = blockIdx.x >> 4;
  const int w    = blockIdx.x & 15;
  const int tid  = threadIdx.x;
  const int wv   = tid >> 6;
  const int lane = tid & 63;

  __shared__ short lx[8*512];
  __shared__ short lh1[16*512];
  __shared__ short lh2[8*512];
  __shared__ float g1[4][16*33];
  __shared__ float g2[4][16*17];
  __shared__ float c1s[16*32];
  __shared__ float c2s[16*16];
  __shared__ float b1s[4][32];
  __shared__ float b2s[4][16];

  for (int i = tid; i < 16*32; i += 256) c1s[i] = 0.f;
  for (int i = tid; i < 16*16; i += 256) c2s[i] = 0.f;
  if (tid < 128) b1s[tid>>5][tid&31] = bc1[(tid>>5)*512 + w*32 + (tid&31)];
  if (tid < 64)  b2s[tid>>4][tid&15] = bc2[(tid>>4)*256 + w*16 + (tid&15)];

  // weights -> registers (compiler may stream from warm L2; acceptable)
  s16x8 W1[2][KS1];
  s16x8 W2[KS2];
  {
    const int nt0 = wv*32 + w*2;
    #pragma unroll
    for (int nt = 0; nt < 2; ++nt)
      #pragma unroll
      for (int ks = 0; ks < KS1; ++ks)
        W1[nt][ks] = *(const s16x8*)(w1p + (((nt0+nt)*KS1 + ks)*64 + lane)*8);
    const int nt2 = wv*16 + w;
    #pragma unroll
    for (int ks = 0; ks < KS2; ++ks)
      W2[ks] = *(const s16x8*)(w2p + ((nt2*KS2 + ks)*64 + lane)*8);
  }

  // prologue: x(t=0); h1_{-1}=0 lives in buffer 1 (pre-zeroed)
  stageN(xsrc + (0*4 + bg)*KXB*512, lx, KXB, wv, lane);
  stageN(h1f + (1*4 + bg)*16*512,  lh1, 16,  wv, lane);
  __syncthreads();

  for (int t = 0; t < T_; ++t){
    // ---- cell1: wave wv = gate wv, cols w*32..+32 ----
    f32x4 acc0 = {0.f,0.f,0.f,0.f}, acc1 = {0.f,0.f,0.f,0.f};
    #pragma unroll
    for (int ks = 0; ks < KS1; ++ks){
      const short* ap = (ks < KXB) ? (lx + ks*512) : (lh1 + (ks-KXB)*512);
      s16x8 a = *(const s16x8*)(ap + lane*8);
      acc0 = mfma_(a, W1[0][ks], acc0);
      acc1 = mfma_(a, W1[1][ks], acc1);
    }
    {
      const int r0 = (lane>>4)*4, cc = lane & 15;
      #pragma unroll
      for (int j = 0; j < 4; ++j){
        g1[wv][(r0+j)*33 + cc]      = acc0[j];
        g1[wv][(r0+j)*33 + 16 + cc] = acc1[j];
      }
    }
    __syncthreads();
    // elementwise: h1 slice [16 rows x 32 cols], 2 outputs/thread
    {
      short* h1dst = h1f + (((t&1)*4 + bg)*16 + w)*512;
      const int idx = tid << 1;
      const int r = idx >> 5;
      const int c = idx & 31;        // even
      float hv0 = 0.f, hv1 = 0.f;
      #pragma unroll
      for (int p = 0; p < 2; ++p){
        const int cp = c + p;
        const float xi = g1[0][r*33+cp] + b1s[0][cp];
        const float xf = g1[1][r*33+cp] + b1s[1][cp];
        const float xg = g1[2][r*33+cp] + b1s[2][cp];
        const float xo = g1[3][r*33+cp] + b1s[3][cp];
        const float ii = sigm_(xi), ff = sigm_(xf), oo = sigm_(xo);
        const float gg = tanh_(xg);
        const float cn = ff * c1s[r*32+cp] + ii * gg;
        c1s[r*32+cp] = cn;
        const float hv = oo * tanh_(cn);
        if (p == 0) hv0 = hv; else hv1 = hv;
      }
      const u32 pk = bf16rne(hv0) | (bf16rne(hv1) << 16);
      stg_cc4(h1dst + ((((c>>3)<<4) + r) << 3) + (c & 7), pk);
    }

    groupbar(bar + bg*128, (u32)t, (u32)(t+1));

    // ---- stage: h1_t (16 blk, cc), h2_{t-1} (8 blk, cc), x_{t+1} (cached) ----
    {
      const short* h1src = h1f + ((t&1)*4 + bg)*16*512 + lane*8;
      const short* h2src = seq + (t*4 + bg)*8*512 + lane*8;
      const int tn = (t+1 < T_) ? (t+1) : (T_-1);
      const short* xs = xsrc + (tn*4 + bg)*KXB*512 + lane*8;
      s16x8 bh1[4], bh2[2], bx[2];
      #pragma unroll
      for (int c = 0; c < 4; ++c) bh1[c] = ldg_cc16(h1src + (c*4+wv)*512);
      #pragma unroll
      for (int c = 0; c < 2; ++c) bh2[c] = ldg_cc16(h2src + (c*4+wv)*512);
      #pragma unroll
      for (int c = 0; c < XB; ++c) bx[c] = *(const s16x8*)(xs + (c*4+wv)*512);
      wait_vm0();
      #pragma unroll
      for (int c = 0; c < 4; ++c) *(s16x8*)(lh1 + (c*4+wv)*512 + lane*8) = bh1[c];
      #pragma unroll
      for (int c = 0; c < 2; ++c) *(s16x8*)(lh2 + (c*4+wv)*512 + lane*8) = bh2[c];
      #pragma unroll
      for (int c = 0; c < XB; ++c) *(s16x8*)(lx + (c*4+wv)*512 + lane*8) = bx[c];
    }
    __syncthreads();

    // ---- cell2: A = [h1_t | h2_{t-1}], wave wv = gate wv, cols w*16..+16 ----
    f32x4 acc = {0.f,0.f,0.f,0.f};
    #pragma unroll
    for (int ks = 0; ks < KS2; ++ks){
      const short* ap = (ks < 16) ? (lh1 + ks*512) : (lh2 + (ks-16)*512);
      s16x8 a = *(const s16x8*)(ap + lane*8);
      acc = mfma_(a, W2[ks], acc);
    }
    {
      const int r0 = (lane>>4)*4, cc = lane & 15;
      #pragma unroll
      for (int j = 0; j < 4; ++j) g2[wv][(r0+j)*17 + cc] = acc[j];
    }
    __syncthreads();
    {
      short* odst = seq + ((t+1)*4 + bg)*8*512;
      const int r = tid >> 4, c = tid & 15;
      const float xi = g2[0][r*17+c] + b2s[0][c];
      const float xf = g2[1][r*17+c] + b2s[1][c];
      const float xg = g2[2][r*17+c] + b2s[2][c];
      const float xo = g2[3][r*17+c] + b2s[3][c];
      const float ii = sigm_(xi), ff = sigm_(xf), oo = sigm_(xo);
      const float gg = tanh_(xg);
      const float cn = ff * c2s[r*16+c] + ii * gg;
      c2s[r*16+c] = cn;
      const float hv = oo * tanh_(cn);
      const int jj = ((w & 1) << 4) + c;           // k-local within 32-block
      stg_cc2(odst + (((w>>1)*64 + ((jj>>3)<<4) + r) << 3) + (jj & 7), bf16rne(hv));
    }
    // no trailing sync needed: next write to lh1/lh2/lx is after next barrier
  }
}

// ---------------------------------------------------------------------------
// fused fc1(relu)+fc2 over one t-slice (64 rows) per block
// ---------------------------------------------------------------------------
__launch_bounds__(256, 1)
__global__ void fc_kernel(const short* __restrict__ dfrag, // [T+1][4][8][512]
                          const short* __restrict__ fc1p,  // [32][8][512]
                          const short* __restrict__ fc2p,  // [8][16][512]
                          const float* __restrict__ fc1b,  // [512]
                          float* __restrict__ out)         // [64][1024][128]
{
  const int t = blockIdx.x;
  const int tid = threadIdx.x, wv = tid >> 6, lane = tid & 63;
  __shared__ short hl[4*16*512];                 // 64KB: h in frag layout
  const short* A = dfrag + (t+1)*4*8*512;

  f32x4 acc[4][8];
  #pragma unroll
  for (int mt = 0; mt < 4; ++mt)
    #pragma unroll
    for (int nt = 0; nt < 8; ++nt) acc[mt][nt] = (f32x4){0.f,0.f,0.f,0.f};

  #pragma unroll
  for (int ks = 0; ks < 8; ++ks){
    s16x8 a[4];
    #pragma unroll
    for (int mt = 0; mt < 4; ++mt) a[mt] = *(const s16x8*)(A + (mt*8+ks)*512 + lane*8);
    #pragma unroll
    for (int nt = 0; nt < 8; ++nt){
      s16x8 b = *(const s16x8*)(fc1p + (((wv*8+nt)*8 + ks)*64 + lane)*8);
      #pragma unroll
      for (int mt = 0; mt < 4; ++mt) acc[mt][nt] = mfma_(a[mt], b, acc[mt][nt]);
    }
  }
  const int r0 = (lane>>4)*4, c15 = lane & 15;
  #pragma unroll
  for (int nt = 0; nt < 8; ++nt){
    const int col = wv*128 + nt*16 + c15;
    const float bia = fc1b[col];
    const int ks2 = col >> 5, lp = (((col & 31) >> 3) << 4), e = col & 7;
    #pragma unroll
    for (int mt = 0; mt < 4; ++mt)
      #pragma unroll
      for (int j = 0; j < 4; ++j){
        float v = acc[mt][nt][j] + bia;
        v = v > 0.f ? v : 0.f;
        hl[(mt*16 + ks2)*512 + (lp + r0 + j)*8 + e] = (short)bf16rne(v);
      }
  }
  __syncthreads();

  f32x4 a2[4][2];
  #pragma unroll
  for (int mt = 0; mt < 4; ++mt)
    #pragma unroll
    for (int nt = 0; nt < 2; ++nt) a2[mt][nt] = (f32x4){0.f,0.f,0.f,0.f};
  #pragma unroll
  for (int ks = 0; ks < 16; ++ks){
    s16x8 a[4];
    #pragma unroll
    for (int mt = 0; mt < 4; ++mt) a[mt] = *(const s16x8*)(hl + (mt*16+ks)*512 + lane*8);
    #pragma unroll
    for (int nt = 0; nt < 2; ++nt){
      s16x8 b = *(const s16x8*)(fc2p + (((wv*2+nt)*16 + ks)*64 + lane)*8);
      #pragma unroll
      for (int mt = 0; mt < 4; ++mt) a2[mt][nt] = mfma_(a[mt], b, a2[mt][nt]);
    }
  }
  #pragma unroll
  for (int mt = 0; mt < 4; ++mt)
    #pragma unroll
    for (int nt = 0; nt < 2; ++nt)
      #pragma unroll
      for (int j = 0; j < 4; ++j){
        const int b_  = mt*16 + r0 + j;
        const int col = wv*32 + nt*16 + c15;
        out[(b_*1024 + t)*128 + col] = a2[mt][nt][j];
      }
}

// ---------------------------------------------------------------------------
// packing kernels
// ---------------------------------------------------------------------------
__global__ void pack_w(const float* __restrict__ src1, int K1,
                       const float* __restrict__ src2, int K2,
                       int N, short* __restrict__ dst)
{
  const int KS = (K1 + K2) >> 5;
  const int total = (N >> 4) * KS * 64;
  const int tid = blockIdx.x*256 + threadIdx.x;
  if (tid >= total) return;
  const int lane = tid & 63;
  const int rest = tid >> 6;
  const int ks = rest % KS;
  const int ntile = rest / KS;
  const int n = ntile*16 + (lane & 15);
  const int k = ks*32 + ((lane >> 4) << 3);
  const float* s; int kk, stride;
  if (k < K1){ s = src1; kk = k;      stride = K1; }
  else       { s = src2; kk = k - K1; stride = K2; }
  const float4 f0 = *(const float4*)(s + n*stride + kk);
  const float4 f1 = *(const float4*)(s + n*stride + kk + 4);
  s16x8 r;
  r[0] = (short)bf16rne(f0.x); r[1] = (short)bf16rne(f0.y);
  r[2] = (short)bf16rne(f0.z); r[3] = (short)bf16rne(f0.w);
  r[4] = (short)bf16rne(f1.x); r[5] = (short)bf16rne(f1.y);
  r[6] = (short)bf16rne(f1.z); r[7] = (short)bf16rne(f1.w);
  *(s16x8*)(dst + tid*8) = r;
}

__global__ void pack_x_k(const float* __restrict__ x, short* __restrict__ xp){
  const int tid = blockIdx.x*256 + threadIdx.x;
  const int lane = tid & 63;
  const int ks = (tid >> 6) & 3;
  const int bg = (tid >> 8) & 3;
  const int t  = tid >> 10;
  const int b  = bg*16 + (lane & 15);
  const int k  = ks*32 + ((lane >> 4) << 3);
  const float* s = x + (b*1024 + t)*128 + k;
  const float4 f0 = *(const float4*)s;
  const float4 f1 = *(const float4*)(s + 4);
  s16x8 r;
  r[0] = (short)bf16rne(f0.x); r[1] = (short)bf16rne(f0.y);
  r[2] = (short)bf16rne(f0.z); r[3] = (short)bf16rne(f0.w);
  r[4] = (short)bf16rne(f1.x); r[5] = (short)bf16rne(f1.y);
  r[6] = (short)bf16rne(f1.z); r[7] = (short)bf16rne(f1.w);
  *(s16x8*)(xp + (size_t)tid*8) = r;
}

__global__ void addv(const float* __restrict__ a, const float* __restrict__ b,
                     float* __restrict__ o, int n){
  const int i = blockIdx.x*256 + threadIdx.x;
  if (i < n) o[i] = a[i] + b[i];
}

// ---------------------------------------------------------------------------
extern "C" void kernel_launch(void* const* d_in, const int* in_sizes, int n_in,
                              void* d_out, int out_size, void* d_ws, size_t ws_size,
                              hipStream_t stream)
{
  (void)in_sizes; (void)n_in; (void)out_size; (void)ws_size;
  const float* x     = (const float*)d_in[0];
  const float* eWih1 = (const float*)d_in[1];
  const float* eWhh1 = (const float*)d_in[2];
  const float* ebih1 = (const float*)d_in[3];
  const float* ebhh1 = (const float*)d_in[4];
  const float* eWih2 = (const float*)d_in[5];
  const float* eWhh2 = (const float*)d_in[6];
  const float* ebih2 = (const float*)d_in[7];
  const float* ebhh2 = (const float*)d_in[8];
  const float* dWih1 = (const float*)d_in[9];
  const float* dWhh1 = (const float*)d_in[10];
  const float* dbih1 = (const float*)d_in[11];
  const float* dbhh1 = (const float*)d_in[12];
  const float* dWih2 = (const float*)d_in[13];
  const float* dWhh2 = (const float*)d_in[14];
  const float* dbih2 = (const float*)d_in[15];
  const float* dbhh2 = (const float*)d_in[16];
  const float* fc1w  = (const float*)d_in[17];
  const float* fc1b  = (const float*)d_in[18];
  const float* fc2w  = (const float*)d_in[19];
  float* out = (float*)d_out;
  char* ws = (char*)d_ws;

  size_t off = 0;
  auto alloc = [&](size_t bytes){ size_t o = off; off += (bytes + 255) & ~(size_t)255; return o; };
  const size_t ENC1P = alloc(128*20*512*2);
  const size_t ENC2P = alloc(64*24*512*2);
  const size_t DEC1P = alloc(128*24*512*2);
  const size_t DEC2P = alloc(64*24*512*2);
  const size_t FC1P  = alloc(32*8*512*2);
  const size_t FC2P  = alloc(8*16*512*2);
  const size_t BC1E  = alloc(2048*4);
  const size_t BC2E  = alloc(1024*4);
  const size_t BC1D  = alloc(2048*4);
  const size_t BC2D  = alloc(1024*4);
  const size_t XP    = alloc((size_t)1024*4*4*512*2);
  const size_t ZFRAG = alloc((size_t)1025*4*8*512*2);
  const size_t DFRAG = alloc((size_t)1025*4*8*512*2);
  const size_t H1E   = alloc(2*4*16*512*2);
  const size_t H1D   = alloc(2*4*16*512*2);
  const size_t BAR   = alloc(8192);

  short* enc1p = (short*)(ws + ENC1P);
  short* enc2p = (short*)(ws + ENC2P);
  short* dec1p = (short*)(ws + DEC1P);
  short* dec2p = (short*)(ws + DEC2P);
  short* fc1p  = (short*)(ws + FC1P);
  short* fc2p  = (short*)(ws + FC2P);
  float* bc1e  = (float*)(ws + BC1E);
  float* bc2e  = (float*)(ws + BC2E);
  float* bc1d  = (float*)(ws + BC1D);
  float* bc2d  = (float*)(ws + BC2D);
  short* xp    = (short*)(ws + XP);
  short* zfrag = (short*)(ws + ZFRAG);
  short* dfrag = (short*)(ws + DFRAG);
  short* h1e   = (short*)(ws + H1E);
  short* h1d   = (short*)(ws + H1D);
  u32*   bar   = (u32*)(ws + BAR);

  hipMemsetAsync(zfrag, 0, 4*8*512*2, stream);
  hipMemsetAsync(dfrag, 0, 4*8*512*2, stream);
  hipMemsetAsync(h1e, 0, 2*4*16*512*2, stream);
  hipMemsetAsync(h1d, 0, 2*4*16*512*2, stream);
  hipMemsetAsync(bar, 0, 8192, stream);

  pack_w<<<640, 256, 0, stream>>>(eWih1, 128, eWhh1, 512, 2048, enc1p);
  pack_w<<<384, 256, 0, stream>>>(eWih2, 512, eWhh2, 256, 1024, enc2p);
  pack_w<<<768, 256, 0, stream>>>(dWih1, 256, dWhh1, 512, 2048, dec1p);
  pack_w<<<384, 256, 0, stream>>>(dWih2, 512, dWhh2, 256, 1024, dec2p);
  pack_w<<<64,  256, 0, stream>>>(fc1w,  256, fc1w,  0,   512,  fc1p);
  pack_w<<<32,  256, 0, stream>>>(fc2w,  512, fc2w,  0,   128,  fc2p);
  addv<<<8, 256, 0, stream>>>(ebih1, ebhh1, bc1e, 2048);
  addv<<<4, 256, 0, stream>>>(ebih2, ebhh2, bc2e, 1024);
  addv<<<8, 256, 0, stream>>>(dbih1, dbhh1, bc1d, 2048);
  addv<<<4, 256, 0, stream>>>(dbih2, dbhh2, bc2d, 1024);
  pack_x_k<<<4096, 256, 0, stream>>>(x, xp);

  scan_kernel<4><<<64, 256, 0, stream>>>(xp, zfrag, h1e, enc1p, enc2p,
                                         bc1e, bc2e, bar);
  scan_kernel<8><<<64, 256, 0, stream>>>(zfrag + 4*8*512, dfrag, h1d, dec1p, dec2p,
                                         bc1d, bc2d, bar + 1024);
  fc_kernel<<<1024, 256, 0, stream>>>(dfrag, fc1p, fc2p, fc1b, out);
}

// Round 3
// 4410.289 us; speedup vs baseline: 4.7691x; 2.3295x over previous
//
#include <hip/hip_runtime.h>
#include <stdint.h>

typedef __attribute__((ext_vector_type(8))) short s16x8;
typedef __attribute__((ext_vector_type(4))) float f32x4;
typedef uint32_t u32;

#define DEV static __device__ __forceinline__

constexpr int T_ = 1024;

DEV u32 bf16rne(float x){
  u32 u = __float_as_uint(x);
  u = (u + 0x7FFFu + ((u >> 16) & 1u)) >> 16;
  return u;
}
DEV float sigm_(float x){ return 1.f / (1.f + __expf(-x)); }
DEV float tanh_(float x){
  float ax = fabsf(x);
  float e = __expf(-2.f * ax);
  float r = (1.f - e) / (1.f + e);
  return x < 0.f ? -r : r;
}
DEV f32x4 mfma_(s16x8 a, s16x8 b, f32x4 c){
  return __builtin_amdgcn_mfma_f32_16x16x32_bf16(a, b, c, 0, 0, 0);
}

// --- system-coherent (LLC-level) access helpers: bypass L1+L2, NO fences ---
DEV s16x8 ldg_cc16(const short* p){
  s16x8 v;
  asm volatile("global_load_dwordx4 %0, %1, off sc0 sc1"
               : "=v"(v) : "v"(p) : "memory");
  return v;
}
DEV void stg_cc4(short* p, u32 v){
  asm volatile("global_store_dword %0, %1, off sc0 sc1"
               : : "v"(p), "v"(v) : "memory");
}
DEV void stg_cc2(short* p, u32 v){
  asm volatile("global_store_short %0, %1, off sc0 sc1"
               : : "v"(p), "v"(v) : "memory");
}
DEV void wait_vm0(){ asm volatile("s_waitcnt vmcnt(0)" ::: "memory"); }

// pin a loaded value into a VGPR quad (non-rematerializable)
DEV void pin(s16x8 &x){ asm volatile("" : "+v"(x)); }

// monotonic single-RTT group barrier: non-returning atomic add + poll
DEV void groupbar(u32* ctr, u32 target, int tid){
  wait_vm0();                          // all this wave's sc stores at LLC
  __syncthreads();                     // => all waves' stores drained
  if (tid == 0){
    __hip_atomic_fetch_add(ctr, 1u, __ATOMIC_RELAXED, __HIP_MEMORY_SCOPE_AGENT);
    while (__hip_atomic_load(ctr, __ATOMIC_RELAXED, __HIP_MEMORY_SCOPE_AGENT) < target)
      __builtin_amdgcn_s_sleep(1);
  }
  __syncthreads();
}

// decoder waits for encoder progress (monotonic counter, relaxed poll)
DEV void wait_enc(const u32* ctr, u32 target, int tid){
  if (tid == 0){
    while (__hip_atomic_load(ctr, __ATOMIC_RELAXED, __HIP_MEMORY_SCOPE_AGENT) < target)
      __builtin_amdgcn_s_sleep(1);
  }
  __syncthreads();
}

// ---------------------------------------------------------------------------
// Fused 2-cell LSTM scan, one batch-group (16 rows) per 16 WGs.
// Fragment layouts: A-block[lane][e] = A[row=lane&15][k=(lane>>4)*8+e]
// DEC=true: x source is the encoder's z sequence (sc loads + enc-progress poll)
// ---------------------------------------------------------------------------
template<int KXB, bool DEC>
DEV void run_scan(const short* __restrict__ xsrc,  // [T][4][KXB][512]
                  short* __restrict__ seq,         // [T+1][4][8][512]
                  short* __restrict__ h1f,         // [2][4][16][512]
                  const short* __restrict__ w1p,
                  const short* __restrict__ w2p,
                  const float* __restrict__ bc1,
                  const float* __restrict__ bc2,
                  u32* mybar, const u32* encbar,
                  int bg, int w,
                  short* lx, short* lh1, short* lh2,
                  float* g1, float* g2, float* c1s, float* c2s,
                  float* b1s, float* b2s)
{
  constexpr int KS1 = KXB + 16;
  constexpr int XB  = KXB/4;
  const int tid  = threadIdx.x;
  const int wv   = tid >> 6;
  const int lane = tid & 63;

  for (int i = tid; i < 16*32; i += 256) c1s[i] = 0.f;
  for (int i = tid; i < 16*16; i += 256) c2s[i] = 0.f;
  if (tid < 128) b1s[tid] = bc1[(tid>>5)*512 + w*32 + (tid&31)];
  if (tid < 64)  b2s[tid] = bc2[(tid>>4)*256 + w*16 + (tid&15)];

  // ---- weights -> pinned VGPRs (persist across all 1024 steps) ----
  s16x8 W1[2][KS1];
  s16x8 W2[24];
  {
    const int nt0 = wv*32 + w*2;
    #pragma unroll
    for (int nt = 0; nt < 2; ++nt)
      #pragma unroll
      for (int ks = 0; ks < KS1; ++ks){
        W1[nt][ks] = *(const s16x8*)(w1p + (((nt0+nt)*KS1 + ks)*64 + lane)*8);
        pin(W1[nt][ks]);
      }
    const int nt2 = wv*16 + w;
    #pragma unroll
    for (int ks = 0; ks < 24; ++ks){
      W2[ks] = *(const s16x8*)(w2p + ((nt2*24 + ks)*64 + lane)*8);
      pin(W2[ks]);
    }
  }

  // ---- prologue: stage h1_{-1} (zeros, parity 1) and x_0 ----
  {
    const short* h1src = h1f + (1*4 + bg)*16*512 + lane*8;
    s16x8 bh1[4];
    #pragma unroll
    for (int c = 0; c < 4; ++c) bh1[c] = ldg_cc16(h1src + (c*4+wv)*512);
    if constexpr (DEC) wait_enc(encbar, 32u, tid);     // z_0 drained
    const short* xs = xsrc + (0*4 + bg)*KXB*512 + lane*8;
    s16x8 bx[XB];
    #pragma unroll
    for (int c = 0; c < XB; ++c)
      bx[c] = DEC ? ldg_cc16(xs + (c*4+wv)*512)
                  : *(const s16x8*)(xs + (c*4+wv)*512);
    wait_vm0();
    #pragma unroll
    for (int c = 0; c < 4; ++c) *(s16x8*)(lh1 + (c*4+wv)*512 + lane*8) = bh1[c];
    #pragma unroll
    for (int c = 0; c < XB; ++c) *(s16x8*)(lx + (c*4+wv)*512 + lane*8) = bx[c];
  }
  __syncthreads();

  for (int t = 0; t < T_; ++t){
    // ---- cell1: wave wv = gate wv, cols w*32..+32, 4 partial accs ----
    f32x4 a0a = {0,0,0,0}, a0b = {0,0,0,0}, a1a = {0,0,0,0}, a1b = {0,0,0,0};
    #pragma unroll
    for (int ks = 0; ks < KS1; ks += 2){
      const short* ap0 = (ks < KXB) ? (lx + ks*512) : (lh1 + (ks-KXB)*512);
      s16x8 a = *(const s16x8*)(ap0 + lane*8);
      a0a = mfma_(a, W1[0][ks], a0a);
      a1a = mfma_(a, W1[1][ks], a1a);
      const short* ap1 = (ks+1 < KXB) ? (lx + (ks+1)*512) : (lh1 + (ks+1-KXB)*512);
      s16x8 b = *(const s16x8*)(ap1 + lane*8);
      a0b = mfma_(b, W1[0][ks+1], a0b);
      a1b = mfma_(b, W1[1][ks+1], a1b);
    }
    {
      const f32x4 acc0 = a0a + a0b, acc1 = a1a + a1b;
      const int r0 = (lane>>4)*4, cc = lane & 15;
      #pragma unroll
      for (int j = 0; j < 4; ++j){
        g1[wv*528 + (r0+j)*33 + cc]      = acc0[j];
        g1[wv*528 + (r0+j)*33 + 16 + cc] = acc1[j];
      }
    }
    __syncthreads();

    // ---- prefetch next x/z (hides under elementwise + barrier) ----
    const int tn = (t+1 < T_) ? (t+1) : (T_-1);
    if constexpr (DEC) wait_enc(encbar, (u32)(16*(tn+2)), tid);
    s16x8 bx[XB];
    {
      const short* xs = xsrc + (tn*4 + bg)*KXB*512 + lane*8;
      #pragma unroll
      for (int c = 0; c < XB; ++c)
        bx[c] = DEC ? ldg_cc16(xs + (c*4+wv)*512)
                    : *(const s16x8*)(xs + (c*4+wv)*512);
    }

    // ---- elementwise: h1 slice [16 x 32], 2 outputs/thread ----
    {
      short* h1dst = h1f + (((t&1)*4 + bg)*16 + w)*512;
      const int idx = tid << 1;
      const int r = idx >> 5;
      const int c = idx & 31;        // even
      float hv0 = 0.f, hv1 = 0.f;
      #pragma unroll
      for (int p = 0; p < 2; ++p){
        const int cp = c + p;
        const float xi = g1[0*528 + r*33+cp] + b1s[0*32+cp];
        const float xf = g1[1*528 + r*33+cp] + b1s[1*32+cp];
        const float xg = g1[2*528 + r*33+cp] + b1s[2*32+cp];
        const float xo = g1[3*528 + r*33+cp] + b1s[3*32+cp];
        const float ii = sigm_(xi), ff = sigm_(xf), oo = sigm_(xo);
        const float gg = tanh_(xg);
        const float cn = ff * c1s[r*32+cp] + ii * gg;
        c1s[r*32+cp] = cn;
        const float hv = oo * tanh_(cn);
        if (p == 0) hv0 = hv; else hv1 = hv;
      }
      const u32 pk = bf16rne(hv0) | (bf16rne(hv1) << 16);
      stg_cc4(h1dst + ((((c>>3)<<4) + r) << 3) + (c & 7), pk);
    }

    groupbar(mybar, (u32)(16*(t+1)), tid);

    // ---- stage: h1_t (16 blk), h2_{t-1} (8 blk) via LLC; x from prefetch ----
    {
      const short* h1src = h1f + ((t&1)*4 + bg)*16*512 + lane*8;
      const short* h2src = seq + (t*4 + bg)*8*512 + lane*8;
      s16x8 bh1[4], bh2[2];
      #pragma unroll
      for (int c = 0; c < 4; ++c) bh1[c] = ldg_cc16(h1src + (c*4+wv)*512);
      #pragma unroll
      for (int c = 0; c < 2; ++c) bh2[c] = ldg_cc16(h2src + (c*4+wv)*512);
      wait_vm0();
      #pragma unroll
      for (int c = 0; c < 4; ++c) *(s16x8*)(lh1 + (c*4+wv)*512 + lane*8) = bh1[c];
      #pragma unroll
      for (int c = 0; c < 2; ++c) *(s16x8*)(lh2 + (c*4+wv)*512 + lane*8) = bh2[c];
      #pragma unroll
      for (int c = 0; c < XB; ++c) *(s16x8*)(lx + (c*4+wv)*512 + lane*8) = bx[c];
    }
    __syncthreads();

    // ---- cell2: A = [h1_t | h2_{t-1}], 2 partial accs ----
    f32x4 aca = {0,0,0,0}, acb = {0,0,0,0};
    #pragma unroll
    for (int ks = 0; ks < 24; ks += 2){
      const short* ap0 = (ks < 16) ? (lh1 + ks*512) : (lh2 + (ks-16)*512);
      s16x8 a = *(const s16x8*)(ap0 + lane*8);
      aca = mfma_(a, W2[ks], aca);
      const short* ap1 = (ks+1 < 16) ? (lh1 + (ks+1)*512) : (lh2 + (ks+1-16)*512);
      s16x8 b = *(const s16x8*)(ap1 + lane*8);
      acb = mfma_(b, W2[ks+1], acb);
    }
    {
      const f32x4 acc = aca + acb;
      const int r0 = (lane>>4)*4, cc = lane & 15;
      #pragma unroll
      for (int j = 0; j < 4; ++j) g2[wv*272 + (r0+j)*17 + cc] = acc[j];
    }
    __syncthreads();
    {
      short* odst = seq + ((t+1)*4 + bg)*8*512;
      const int r = tid >> 4, c = tid & 15;
      const float xi = g2[0*272 + r*17+c] + b2s[0*16+c];
      const float xf = g2[1*272 + r*17+c] + b2s[1*16+c];
      const float xg = g2[2*272 + r*17+c] + b2s[2*16+c];
      const float xo = g2[3*272 + r*17+c] + b2s[3*16+c];
      const float ii = sigm_(xi), ff = sigm_(xf), oo = sigm_(xo);
      const float gg = tanh_(xg);
      const float cn = ff * c2s[r*16+c] + ii * gg;
      c2s[r*16+c] = cn;
      const float hv = oo * tanh_(cn);
      const int jj = ((w & 1) << 4) + c;
      stg_cc2(odst + (((w>>1)*64 + ((jj>>3)<<4) + r) << 3) + (jj & 7), bf16rne(hv));
    }
    // next write to lx/lh1/lh2 happens after next groupbar -> safe
  }

  if constexpr (!DEC){
    // signal final cell2 (z_1023) stores drained: ctr reaches 16*1025
    wait_vm0();
    __syncthreads();
    if (tid == 0)
      __hip_atomic_fetch_add(mybar, 1u, __ATOMIC_RELAXED, __HIP_MEMORY_SCOPE_AGENT);
  }
}

// fused encoder+decoder scan: blocks 0..63 = encoder, 64..127 = decoder
// decoder chases encoder via the encoder group's arrival counter (lag 2 steps)
__launch_bounds__(256, 1)
__global__ void scan2(const short* __restrict__ xp,
                      short* __restrict__ zfrag, short* __restrict__ dfrag,
                      short* __restrict__ h1e, short* __restrict__ h1d,
                      const short* __restrict__ enc1p, const short* __restrict__ enc2p,
                      const short* __restrict__ dec1p, const short* __restrict__ dec2p,
                      const float* __restrict__ bc1e, const float* __restrict__ bc2e,
                      const float* __restrict__ bc1d, const float* __restrict__ bc2d,
                      u32* __restrict__ bar)
{
  __shared__ short lx[8*512];
  __shared__ short lh1[16*512];
  __shared__ short lh2[8*512];
  __shared__ float g1[4*528];
  __shared__ float g2[4*272];
  __shared__ float c1s[16*32];
  __shared__ float c2s[16*16];
  __shared__ float b1s[128];
  __shared__ float b2s[64];

  const int b = blockIdx.x;
  if (b < 64){
    run_scan<4, false>(xp, zfrag, h1e, enc1p, enc2p, bc1e, bc2e,
                       bar + (b>>4)*64, nullptr, b>>4, b&15,
                       lx, lh1, lh2, g1, g2, c1s, c2s, b1s, b2s);
  } else {
    const int bb = b - 64;
    run_scan<8, true>(zfrag + 4*8*512, dfrag, h1d, dec1p, dec2p, bc1d, bc2d,
                      bar + (4 + (bb>>4))*64, bar + (bb>>4)*64, bb>>4, bb&15,
                      lx, lh1, lh2, g1, g2, c1s, c2s, b1s, b2s);
  }
}

// ---------------------------------------------------------------------------
// fused fc1(relu)+fc2 over one t-slice (64 rows) per block
// ---------------------------------------------------------------------------
__launch_bounds__(256, 1)
__global__ void fc_kernel(const short* __restrict__ dfrag, // [T+1][4][8][512]
                          const short* __restrict__ fc1p,  // [32][8][512]
                          const short* __restrict__ fc2p,  // [8][16][512]
                          const float* __restrict__ fc1b,  // [512]
                          float* __restrict__ out)         // [64][1024][128]
{
  const int t = blockIdx.x;
  const int tid = threadIdx.x, wv = tid >> 6, lane = tid & 63;
  __shared__ short hl[4*16*512];
  const short* A = dfrag + (t+1)*4*8*512;

  f32x4 acc[4][8];
  #pragma unroll
  for (int mt = 0; mt < 4; ++mt)
    #pragma unroll
    for (int nt = 0; nt < 8; ++nt) acc[mt][nt] = (f32x4){0.f,0.f,0.f,0.f};

  #pragma unroll
  for (int ks = 0; ks < 8; ++ks){
    s16x8 a[4];
    #pragma unroll
    for (int mt = 0; mt < 4; ++mt) a[mt] = *(const s16x8*)(A + (mt*8+ks)*512 + lane*8);
    #pragma unroll
    for (int nt = 0; nt < 8; ++nt){
      s16x8 b = *(const s16x8*)(fc1p + (((wv*8+nt)*8 + ks)*64 + lane)*8);
      #pragma unroll
      for (int mt = 0; mt < 4; ++mt) acc[mt][nt] = mfma_(a[mt], b, acc[mt][nt]);
    }
  }
  const int r0 = (lane>>4)*4, c15 = lane & 15;
  #pragma unroll
  for (int nt = 0; nt < 8; ++nt){
    const int col = wv*128 + nt*16 + c15;
    const float bia = fc1b[col];
    const int ks2 = col >> 5, lp = (((col & 31) >> 3) << 4), e = col & 7;
    #pragma unroll
    for (int mt = 0; mt < 4; ++mt)
      #pragma unroll
      for (int j = 0; j < 4; ++j){
        float v = acc[mt][nt][j] + bia;
        v = v > 0.f ? v : 0.f;
        hl[(mt*16 + ks2)*512 + (lp + r0 + j)*8 + e] = (short)bf16rne(v);
      }
  }
  __syncthreads();

  f32x4 a2[4][2];
  #pragma unroll
  for (int mt = 0; mt < 4; ++mt)
    #pragma unroll
    for (int nt = 0; nt < 2; ++nt) a2[mt][nt] = (f32x4){0.f,0.f,0.f,0.f};
  #pragma unroll
  for (int ks = 0; ks < 16; ++ks){
    s16x8 a[4];
    #pragma unroll
    for (int mt = 0; mt < 4; ++mt) a[mt] = *(const s16x8*)(hl + (mt*16+ks)*512 + lane*8);
    #pragma unroll
    for (int nt = 0; nt < 2; ++nt){
      s16x8 b = *(const s16x8*)(fc2p + (((wv*2+nt)*16 + ks)*64 + lane)*8);
      #pragma unroll
      for (int mt = 0; mt < 4; ++mt) a2[mt][nt] = mfma_(a[mt], b, a2[mt][nt]);
    }
  }
  #pragma unroll
  for (int mt = 0; mt < 4; ++mt)
    #pragma unroll
    for (int nt = 0; nt < 2; ++nt)
      #pragma unroll
      for (int j = 0; j < 4; ++j){
        const int b_  = mt*16 + r0 + j;
        const int col = wv*32 + nt*16 + c15;
        out[(b_*1024 + t)*128 + col] = a2[mt][nt][j];
      }
}

// ---------------------------------------------------------------------------
// packing kernels
// ---------------------------------------------------------------------------
__global__ void pack_w(const float* __restrict__ src1, int K1,
                       const float* __restrict__ src2, int K2,
                       int N, short* __restrict__ dst)
{
  const int KS = (K1 + K2) >> 5;
  const int total = (N >> 4) * KS * 64;
  const int tid = blockIdx.x*256 + threadIdx.x;
  if (tid >= total) return;
  const int lane = tid & 63;
  const int rest = tid >> 6;
  const int ks = rest % KS;
  const int ntile = rest / KS;
  const int n = ntile*16 + (lane & 15);
  const int k = ks*32 + ((lane >> 4) << 3);
  const float* s; int kk, stride;
  if (k < K1){ s = src1; kk = k;      stride = K1; }
  else       { s = src2; kk = k - K1; stride = K2; }
  const float4 f0 = *(const float4*)(s + n*stride + kk);
  const float4 f1 = *(const float4*)(s + n*stride + kk + 4);
  s16x8 r;
  r[0] = (short)bf16rne(f0.x); r[1] = (short)bf16rne(f0.y);
  r[2] = (short)bf16rne(f0.z); r[3] = (short)bf16rne(f0.w);
  r[4] = (short)bf16rne(f1.x); r[5] = (short)bf16rne(f1.y);
  r[6] = (short)bf16rne(f1.z); r[7] = (short)bf16rne(f1.w);
  *(s16x8*)(dst + tid*8) = r;
}

__global__ void pack_x_k(const float* __restrict__ x, short* __restrict__ xp){
  const int tid = blockIdx.x*256 + threadIdx.x;
  const int lane = tid & 63;
  const int ks = (tid >> 6) & 3;
  const int bg = (tid >> 8) & 3;
  const int t  = tid >> 10;
  const int b  = bg*16 + (lane & 15);
  const int k  = ks*32 + ((lane >> 4) << 3);
  const float* s = x + (b*1024 + t)*128 + k;
  const float4 f0 = *(const float4*)s;
  const float4 f1 = *(const float4*)(s + 4);
  s16x8 r;
  r[0] = (short)bf16rne(f0.x); r[1] = (short)bf16rne(f0.y);
  r[2] = (short)bf16rne(f0.z); r[3] = (short)bf16rne(f0.w);
  r[4] = (short)bf16rne(f1.x); r[5] = (short)bf16rne(f1.y);
  r[6] = (short)bf16rne(f1.z); r[7] = (short)bf16rne(f1.w);
  *(s16x8*)(xp + (size_t)tid*8) = r;
}

__global__ void addv(const float* __restrict__ a, const float* __restrict__ b,
                     float* __restrict__ o, int n){
  const int i = blockIdx.x*256 + threadIdx.x;
  if (i < n) o[i] = a[i] + b[i];
}

// ---------------------------------------------------------------------------
extern "C" void kernel_launch(void* const* d_in, const int* in_sizes, int n_in,
                              void* d_out, int out_size, void* d_ws, size_t ws_size,
                              hipStream_t stream)
{
  (void)in_sizes; (void)n_in; (void)out_size; (void)ws_size;
  const float* x     = (const float*)d_in[0];
  const float* eWih1 = (const float*)d_in[1];
  const float* eWhh1 = (const float*)d_in[2];
  const float* ebih1 = (const float*)d_in[3];
  const float* ebhh1 = (const float*)d_in[4];
  const float* eWih2 = (const float*)d_in[5];
  const float* eWhh2 = (const float*)d_in[6];
  const float* ebih2 = (const float*)d_in[7];
  const float* ebhh2 = (const float*)d_in[8];
  const float* dWih1 = (const float*)d_in[9];
  const float* dWhh1 = (const float*)d_in[10];
  const float* dbih1 = (const float*)d_in[11];
  const float* dbhh1 = (const float*)d_in[12];
  const float* dWih2 = (const float*)d_in[13];
  const float* dWhh2 = (const float*)d_in[14];
  const float* dbih2 = (const float*)d_in[15];
  const float* dbhh2 = (const float*)d_in[16];
  const float* fc1w  = (const float*)d_in[17];
  const float* fc1b  = (const float*)d_in[18];
  const float* fc2w  = (const float*)d_in[19];
  float* out = (float*)d_out;
  char* ws = (char*)d_ws;

  size_t off = 0;
  auto alloc = [&](size_t bytes){ size_t o = off; off += (bytes + 255) & ~(size_t)255; return o; };
  const size_t ENC1P = alloc(128*20*512*2);
  const size_t ENC2P = alloc(64*24*512*2);
  const size_t DEC1P = alloc(128*24*512*2);
  const size_t DEC2P = alloc(64*24*512*2);
  const size_t FC1P  = alloc(32*8*512*2);
  const size_t FC2P  = alloc(8*16*512*2);
  const size_t BC1E  = alloc(2048*4);
  const size_t BC2E  = alloc(1024*4);
  const size_t BC1D  = alloc(2048*4);
  const size_t BC2D  = alloc(1024*4);
  const size_t XP    = alloc((size_t)1024*4*4*512*2);
  const size_t ZFRAG = alloc((size_t)1025*4*8*512*2);
  const size_t DFRAG = alloc((size_t)1025*4*8*512*2);
  const size_t H1E   = alloc(2*4*16*512*2);
  const size_t H1D   = alloc(2*4*16*512*2);
  const size_t BAR   = alloc(8192);

  short* enc1p = (short*)(ws + ENC1P);
  short* enc2p = (short*)(ws + ENC2P);
  short* dec1p = (short*)(ws + DEC1P);
  short* dec2p = (short*)(ws + DEC2P);
  short* fc1p  = (short*)(ws + FC1P);
  short* fc2p  = (short*)(ws + FC2P);
  float* bc1e  = (float*)(ws + BC1E);
  float* bc2e  = (float*)(ws + BC2E);
  float* bc1d  = (float*)(ws + BC1D);
  float* bc2d  = (float*)(ws + BC2D);
  short* xp    = (short*)(ws + XP);
  short* zfrag = (short*)(ws + ZFRAG);
  short* dfrag = (short*)(ws + DFRAG);
  short* h1e   = (short*)(ws + H1E);
  short* h1d   = (short*)(ws + H1D);
  u32*   bar   = (u32*)(ws + BAR);

  hipMemsetAsync(zfrag, 0, 4*8*512*2, stream);
  hipMemsetAsync(dfrag, 0, 4*8*512*2, stream);
  hipMemsetAsync(h1e, 0, 2*4*16*512*2, stream);
  hipMemsetAsync(h1d, 0, 2*4*16*512*2, stream);
  hipMemsetAsync(bar, 0, 8192, stream);

  pack_w<<<640, 256, 0, stream>>>(eWih1, 128, eWhh1, 512, 2048, enc1p);
  pack_w<<<384, 256, 0, stream>>>(eWih2, 512, eWhh2, 256, 1024, enc2p);
  pack_w<<<768, 256, 0, stream>>>(dWih1, 256, dWhh1, 512, 2048, dec1p);
  pack_w<<<384, 256, 0, stream>>>(dWih2, 512, dWhh2, 256, 1024, dec2p);
  pack_w<<<64,  256, 0, stream>>>(fc1w,  256, fc1w,  0,   512,  fc1p);
  pack_w<<<32,  256, 0, stream>>>(fc2w,  512, fc2w,  0,   128,  fc2p);
  addv<<<8, 256, 0, stream>>>(ebih1, ebhh1, bc1e, 2048);
  addv<<<4, 256, 0, stream>>>(ebih2, ebhh2, bc2e, 1024);
  addv<<<8, 256, 0, stream>>>(dbih1, dbhh1, bc1d, 2048);
  addv<<<4, 256, 0, stream>>>(dbih2, dbhh2, bc2d, 1024);
  pack_x_k<<<4096, 256, 0, stream>>>(x, xp);

  // fused pipelined encoder+decoder scan
  scan2<<<128, 256, 0, stream>>>(xp, zfrag, dfrag, h1e, h1d,
                                 enc1p, enc2p, dec1p, dec2p,
                                 bc1e, bc2e, bc1d, bc2d, bar);
  fc_kernel<<<1024, 256, 0, stream>>>(dfrag, fc1p, fc2p, fc1b, out);
}